// Round 1
// baseline (2596.251 us; speedup 1.0000x reference)
//
#include <hip/hip_runtime.h>
#include <math.h>

#define HID 64
#define LN_EPS 1e-5f
#define NORM_EPS 1e-12f

__device__ __forceinline__ float wave_sum64(float v) {
#pragma unroll
    for (int o = 32; o > 0; o >>= 1) v += __shfl_xor(v, o, 64);
    return v;
}

// ---------------- degree accumulation ----------------
__global__ __launch_bounds__(256) void deg_kernel(const int* __restrict__ src,
                                                  const int* __restrict__ dst,
                                                  float* __restrict__ deg_out,
                                                  float* __restrict__ deg_in,
                                                  int E) {
    int e = blockIdx.x * 256 + threadIdx.x;
    if (e >= E) return;
    atomicAdd(&deg_out[src[e]], 1.0f);
    atomicAdd(&deg_in[dst[e]], 1.0f);
}

// deg -> deg^-0.5 with clamp(deg,1)
__global__ __launch_bounds__(256) void norm_kernel(float* __restrict__ ns,
                                                   float* __restrict__ nd,
                                                   int N) {
    int n = blockIdx.x * 256 + threadIdx.x;
    if (n >= N) return;
    ns[n] = rsqrtf(fmaxf(ns[n], 1.0f));
    nd[n] = rsqrtf(fmaxf(nd[n], 1.0f));
}

// ---------------- edge scatter: agg[dst] += x[src] * ns[src] ----------------
// 16 threads per edge, each handles 4 consecutive floats (float4).
__global__ __launch_bounds__(256) void scatter_kernel(const float* __restrict__ x,
                                                      const int* __restrict__ src,
                                                      const int* __restrict__ dst,
                                                      const float* __restrict__ ns,
                                                      float* __restrict__ agg,
                                                      int E) {
    int tid = blockIdx.x * 256 + threadIdx.x;
    int e = tid >> 4;
    if (e >= E) return;
    int q = tid & 15;
    int s = src[e];
    int t = dst[e];
    float w = ns[s];
    float4 v = reinterpret_cast<const float4*>(x + (size_t)s * HID)[q];
    float* ap = agg + (size_t)t * HID + q * 4;
    atomicAdd(ap + 0, v.x * w);
    atomicAdd(ap + 1, v.y * w);
    atomicAdd(ap + 2, v.z * w);
    atomicAdd(ap + 3, v.w * w);
}

// ---------------- per-node: (agg*nd) @ W + b -> LN -> relu ----------------
// 256 threads = 4 waves; wave handles one node; W staged in LDS.
__global__ __launch_bounds__(256) void conv_dense_kernel(const float* __restrict__ agg,
                                                         const float* __restrict__ nd,
                                                         const float* __restrict__ W,
                                                         const float* __restrict__ b,
                                                         const float* __restrict__ gam,
                                                         const float* __restrict__ bet,
                                                         float* __restrict__ out,
                                                         int N) {
    __shared__ float Ws[HID * HID];
    __shared__ float ts[4][HID];
    int tid = threadIdx.x;
    // cooperative load of W (4096 floats) as float4
    for (int i = tid; i < HID * HID / 4; i += 256) {
        reinterpret_cast<float4*>(Ws)[i] = reinterpret_cast<const float4*>(W)[i];
    }
    int wave = tid >> 6;
    int lane = tid & 63;
    int n = blockIdx.x * 4 + wave;
    float t = 0.0f;
    if (n < N) t = agg[(size_t)n * HID + lane] * nd[n];
    __syncthreads();
    ts[wave][lane] = t;
    __syncthreads();
    if (n >= N) return;

    float y = b[lane];
#pragma unroll 8
    for (int k = 0; k < HID; ++k) {
        y = fmaf(ts[wave][k], Ws[k * HID + lane], y);
    }
    // LayerNorm over the 64 lanes
    float mu = wave_sum64(y) * (1.0f / HID);
    float d = y - mu;
    float var = wave_sum64(d * d) * (1.0f / HID);
    float o = d * rsqrtf(var + LN_EPS) * gam[lane] + bet[lane];
    o = fmaxf(o, 0.0f);
    out[(size_t)n * HID + lane] = o;
}

// ---------------- per-graph pooling: sum, count, max ----------------
__global__ __launch_bounds__(256) void pool_kernel(const float* __restrict__ h1,
                                                   const int* __restrict__ gid,
                                                   float* __restrict__ gsum,
                                                   int* __restrict__ gmax,   // float bits, values >= 0
                                                   float* __restrict__ gcnt,
                                                   int N) {
    int tid = blockIdx.x * 256 + threadIdx.x;
    int n = tid >> 6;
    if (n >= N) return;
    int lane = tid & 63;
    int g = gid[n];
    float v = h1[(size_t)n * HID + lane];
    atomicAdd(&gsum[(size_t)g * HID + lane], v);
    atomicMax(&gmax[(size_t)g * HID + lane], __float_as_int(v));  // v >= 0 (post-relu)
    if (lane == 0) atomicAdd(&gcnt[g], 1.0f);
}

// ---------------- head MLP: one wave (64 threads) per graph ----------------
__global__ __launch_bounds__(64) void head_kernel(const float* __restrict__ gsum,
                                                  const int* __restrict__ gmax,
                                                  const float* __restrict__ gcnt,
                                                  const float* __restrict__ Wc1,
                                                  const float* __restrict__ bc1,
                                                  const float* __restrict__ g3,
                                                  const float* __restrict__ be3,
                                                  const float* __restrict__ Wc2,
                                                  const float* __restrict__ bc2,
                                                  const float* __restrict__ g4,
                                                  const float* __restrict__ be4,
                                                  const float* __restrict__ Wc3,
                                                  const float* __restrict__ bc3,
                                                  float* __restrict__ out) {
    __shared__ float hg[2 * HID];
    __shared__ float t1[HID];
    int g = blockIdx.x;
    int lane = threadIdx.x;

    float cnt = fmaxf(gcnt[g], 1.0f);
    float mean = gsum[(size_t)g * HID + lane] / cnt;
    float mx = __int_as_float(gmax[(size_t)g * HID + lane]);

    float s1 = sqrtf(wave_sum64(mean * mean));
    float a = mean / fmaxf(s1, NORM_EPS);
    float s2 = sqrtf(wave_sum64(mx * mx));
    float bmx = mx / fmaxf(s2, NORM_EPS);

    hg[lane] = a;
    hg[HID + lane] = bmx;
    __syncthreads();

    // y1 = hg @ Wc1 + bc1 ; LN(g3,be3); relu
    float y = bc1[lane];
#pragma unroll 8
    for (int k = 0; k < 2 * HID; ++k) {
        y = fmaf(hg[k], Wc1[k * HID + lane], y);
    }
    float mu = wave_sum64(y) * (1.0f / HID);
    float d = y - mu;
    float var = wave_sum64(d * d) * (1.0f / HID);
    float o = d * rsqrtf(var + LN_EPS) * g3[lane] + be3[lane];
    o = fmaxf(o, 0.0f);
    t1[lane] = o;
    __syncthreads();

    // y2 = t1 @ Wc2 + bc2 ; LN(g4,be4); relu
    float y2 = bc2[lane];
#pragma unroll 8
    for (int k = 0; k < HID; ++k) {
        y2 = fmaf(t1[k], Wc2[k * HID + lane], y2);
    }
    mu = wave_sum64(y2) * (1.0f / HID);
    d = y2 - mu;
    var = wave_sum64(d * d) * (1.0f / HID);
    o = d * rsqrtf(var + LN_EPS) * g4[lane] + be4[lane];
    o = fmaxf(o, 0.0f);

    // out = o @ Wc3 + bc3  (N_CLASSES = 1)
    float v = o * Wc3[lane];
    v = wave_sum64(v);
    if (lane == 0) out[g] = v + bc3[0];
}

extern "C" void kernel_launch(void* const* d_in, const int* in_sizes, int n_in,
                              void* d_out, int out_size, void* d_ws, size_t ws_size,
                              hipStream_t stream) {
    const float* h   = (const float*)d_in[0];
    const int*   src = (const int*)d_in[1];
    const int*   dst = (const int*)d_in[2];
    const int*   gid = (const int*)d_in[3];
    const float* W1  = (const float*)d_in[4];
    const float* b1  = (const float*)d_in[5];
    const float* W2  = (const float*)d_in[6];
    const float* b2  = (const float*)d_in[7];
    const float* g1  = (const float*)d_in[8];
    const float* be1 = (const float*)d_in[9];
    const float* g2  = (const float*)d_in[10];
    const float* be2 = (const float*)d_in[11];
    const float* g3  = (const float*)d_in[12];
    const float* be3 = (const float*)d_in[13];
    const float* g4  = (const float*)d_in[14];
    const float* be4 = (const float*)d_in[15];
    const float* Wc1 = (const float*)d_in[16];
    const float* bc1 = (const float*)d_in[17];
    const float* Wc2 = (const float*)d_in[18];
    const float* bc2 = (const float*)d_in[19];
    const float* Wc3 = (const float*)d_in[20];
    const float* bc3 = (const float*)d_in[21];
    float* out = (float*)d_out;

    const int N = in_sizes[0] / HID;   // 100000
    const int E = in_sizes[1];         // 1200000
    const int G = out_size;            // 512 (N_CLASSES = 1)

    // workspace layout (floats)
    float* ws   = (float*)d_ws;
    float* ns   = ws;                          // N
    float* nd   = ns + N;                      // N
    float* agg  = nd + N;                      // N*64
    float* h1   = agg + (size_t)N * HID;       // N*64
    float* gsum = h1 + (size_t)N * HID;        // G*64
    int*   gmax = (int*)(gsum + (size_t)G * HID);   // G*64 (float bits)
    float* gcnt = (float*)(gmax + (size_t)G * HID); // G

    // zero: degrees, agg, pooling buffers (gsum|gmax|gcnt contiguous = G*129)
    hipMemsetAsync(ns, 0, sizeof(float) * (size_t)2 * N, stream);
    hipMemsetAsync(agg, 0, sizeof(float) * (size_t)N * HID, stream);
    hipMemsetAsync(gsum, 0, sizeof(float) * (size_t)G * (2 * HID + 1), stream);

    // degrees -> normalizers
    deg_kernel<<<(E + 255) / 256, 256, 0, stream>>>(src, dst, ns, nd, E);
    norm_kernel<<<(N + 255) / 256, 256, 0, stream>>>(ns, nd, N);

    // conv1
    scatter_kernel<<<((size_t)E * 16 + 255) / 256, 256, 0, stream>>>(h, src, dst, ns, agg, E);
    conv_dense_kernel<<<(N + 3) / 4, 256, 0, stream>>>(agg, nd, W1, b1, g1, be1, h1, N);

    // conv2
    hipMemsetAsync(agg, 0, sizeof(float) * (size_t)N * HID, stream);
    scatter_kernel<<<((size_t)E * 16 + 255) / 256, 256, 0, stream>>>(h1, src, dst, ns, agg, E);
    conv_dense_kernel<<<(N + 3) / 4, 256, 0, stream>>>(agg, nd, W2, b2, g2, be2, h1, N);

    // pooling
    pool_kernel<<<(N + 3) / 4, 256, 0, stream>>>(h1, gid, gsum, gmax, gcnt, N);

    // head
    head_kernel<<<G, 64, 0, stream>>>(gsum, gmax, gcnt, Wc1, bc1, g3, be3,
                                      Wc2, bc2, g4, be4, Wc3, bc3, out);
}

// Round 3
// 623.433 us; speedup vs baseline: 4.1644x; 4.1644x over previous
//
#include <hip/hip_runtime.h>
#include <math.h>

#define HID 64
#define LN_EPS 1e-5f
#define NORM_EPS 1e-12f
#define CHUNK 1024

__device__ __forceinline__ float wave_sum64(float v) {
#pragma unroll
    for (int o = 32; o > 0; o >>= 1) v += __shfl_xor(v, o, 64);
    return v;
}

// ---------------- edge count (int histograms) ----------------
__global__ __launch_bounds__(256) void count_kernel(const int* __restrict__ src,
                                                    const int* __restrict__ dst,
                                                    int* __restrict__ cnt_out,
                                                    int* __restrict__ cnt_in,
                                                    int E) {
    int e = blockIdx.x * 256 + threadIdx.x;
    if (e >= E) return;
    atomicAdd(&cnt_out[src[e]], 1);
    atomicAdd(&cnt_in[dst[e]], 1);
}

// counts -> deg^-0.5 (clamp 1); also zero cnt_out for reuse as fill cursor
__global__ __launch_bounds__(256) void norm_kernel(int* __restrict__ cnt_out,
                                                   const int* __restrict__ cnt_in,
                                                   float* __restrict__ ns,
                                                   float* __restrict__ nd,
                                                   int N) {
    int n = blockIdx.x * 256 + threadIdx.x;
    if (n >= N) return;
    ns[n] = rsqrtf((float)max(cnt_out[n], 1));
    nd[n] = rsqrtf((float)max(cnt_in[n], 1));
    cnt_out[n] = 0;  // reuse as cursor in fill_kernel
}

// ---------------- 2-level exclusive scan of cnt_in -> cs ----------------
__global__ __launch_bounds__(256) void scan1_kernel(const int* __restrict__ cnt,
                                                    int* __restrict__ cs,
                                                    int* __restrict__ partials,
                                                    int N) {
    __shared__ int wsum[4];
    int t = threadIdx.x;
    int lane = t & 63, wave = t >> 6;
    int base = blockIdx.x * CHUNK + t * 4;
    int v0 = (base + 0 < N) ? cnt[base + 0] : 0;
    int v1 = (base + 1 < N) ? cnt[base + 1] : 0;
    int v2 = (base + 2 < N) ? cnt[base + 2] : 0;
    int v3 = (base + 3 < N) ? cnt[base + 3] : 0;
    int tsum = v0 + v1 + v2 + v3;
    int x = tsum;
#pragma unroll
    for (int off = 1; off < 64; off <<= 1) {
        int y = __shfl_up(x, off, 64);
        if (lane >= off) x += y;
    }
    if (lane == 63) wsum[wave] = x;
    __syncthreads();
    int waveoff = 0;
    for (int w = 0; w < wave; ++w) waveoff += wsum[w];
    int off0 = waveoff + x - tsum;  // exclusive offset for this thread's 4 elems
    if (base + 0 < N) cs[base + 0] = off0;
    if (base + 1 < N) cs[base + 1] = off0 + v0;
    if (base + 2 < N) cs[base + 2] = off0 + v0 + v1;
    if (base + 3 < N) cs[base + 3] = off0 + v0 + v1 + v2;
    if (t == 255) partials[blockIdx.x] = waveoff + x;  // block total
}

// scan2: single block, exclusive scan of partials (up to 1024 chunks)
__global__ __launch_bounds__(256) void scan2_kernel(int* __restrict__ partials, int nch) {
    __shared__ int wsum[4];
    int t = threadIdx.x;
    int lane = t & 63, wave = t >> 6;
    int base = t * 4;
    int v0 = (base + 0 < nch) ? partials[base + 0] : 0;
    int v1 = (base + 1 < nch) ? partials[base + 1] : 0;
    int v2 = (base + 2 < nch) ? partials[base + 2] : 0;
    int v3 = (base + 3 < nch) ? partials[base + 3] : 0;
    int tsum = v0 + v1 + v2 + v3;
    int x = tsum;
#pragma unroll
    for (int off = 1; off < 64; off <<= 1) {
        int y = __shfl_up(x, off, 64);
        if (lane >= off) x += y;
    }
    if (lane == 63) wsum[wave] = x;
    __syncthreads();
    int waveoff = 0;
    for (int w = 0; w < wave; ++w) waveoff += wsum[w];
    int off0 = waveoff + x - tsum;
    if (base + 0 < nch) partials[base + 0] = off0;
    if (base + 1 < nch) partials[base + 1] = off0 + v0;
    if (base + 2 < nch) partials[base + 2] = off0 + v0 + v1;
    if (base + 3 < nch) partials[base + 3] = off0 + v0 + v1 + v2;
}

// scan3: add chunk offsets; write cs[N] = E
__global__ __launch_bounds__(256) void scan3_kernel(int* __restrict__ cs,
                                                    const int* __restrict__ partials,
                                                    int N, int E) {
    int n = blockIdx.x * 256 + threadIdx.x;
    if (n < N) cs[n] += partials[n / CHUNK];
    if (n == 0) cs[N] = E;
}

// ---------------- fill CSR buckets: epack[slot] = (src, ns[src]) ----------------
__global__ __launch_bounds__(256) void fill_kernel(const int* __restrict__ src,
                                                   const int* __restrict__ dst,
                                                   const float* __restrict__ ns,
                                                   const int* __restrict__ cs,
                                                   int* __restrict__ cursor,
                                                   int2* __restrict__ epack,
                                                   int E) {
    int e = blockIdx.x * 256 + threadIdx.x;
    if (e >= E) return;
    int s = src[e];
    int d = dst[e];
    float w = ns[s];
    int p = cs[d] + atomicAdd(&cursor[d], 1);
    epack[p] = make_int2(s, __float_as_int(w));
}

// ---------------- fused conv: gather + (·nd)@W + b -> LN -> relu ----------------
// 256 threads = 4 waves; one wave per node; W staged in LDS.
__global__ __launch_bounds__(256) void conv_kernel(const float* __restrict__ x,
                                                   const int2* __restrict__ epack,
                                                   const int* __restrict__ cs,
                                                   const float* __restrict__ nd,
                                                   const float* __restrict__ W,
                                                   const float* __restrict__ b,
                                                   const float* __restrict__ gam,
                                                   const float* __restrict__ bet,
                                                   float* __restrict__ out,
                                                   int N) {
    __shared__ float Ws[HID * HID];
    __shared__ float ts[4][HID];
    int tid = threadIdx.x;
    for (int i = tid; i < HID * HID / 4; i += 256) {
        reinterpret_cast<float4*>(Ws)[i] = reinterpret_cast<const float4*>(W)[i];
    }
    int wave = tid >> 6;
    int lane = tid & 63;
    int n = blockIdx.x * 4 + wave;

    float acc = 0.0f;
    float t = 0.0f;
    if (n < N) {
        int beg = cs[n], end = cs[n + 1];
        for (int e = beg; e < end; ++e) {
            int2 p = epack[e];  // wave-uniform 8B broadcast load
            acc = fmaf(x[(size_t)p.x * HID + lane], __int_as_float(p.y), acc);
        }
        t = acc * nd[n];
    }
    __syncthreads();  // Ws ready
    if (n >= N) return;
    ts[wave][lane] = t;  // wave-local LDS scratch

    float y = b[lane];
#pragma unroll 8
    for (int k = 0; k < HID; ++k) {
        y = fmaf(ts[wave][k], Ws[k * HID + lane], y);
    }
    float mu = wave_sum64(y) * (1.0f / HID);
    float d = y - mu;
    float var = wave_sum64(d * d) * (1.0f / HID);
    float o = d * rsqrtf(var + LN_EPS) * gam[lane] + bet[lane];
    o = fmaxf(o, 0.0f);
    out[(size_t)n * HID + lane] = o;
}

// ---------------- segmented pooling over sorted graph_ids ----------------
__global__ __launch_bounds__(256) void pool_kernel(const float* __restrict__ h1,
                                                   const int* __restrict__ gid,
                                                   float* __restrict__ gsum,
                                                   int* __restrict__ gmax,   // float bits, vals >= 0
                                                   float* __restrict__ gcnt,
                                                   int N) {
    int wave = threadIdx.x >> 6;
    int lane = threadIdx.x & 63;
    int strip = blockIdx.x * 4 + wave;
    int base = strip * 64;
    if (base >= N) return;
    int nmax = min(64, N - base);
    int gv = (base + lane < N) ? gid[base + lane] : -1;  // coalesced gid strip
    int gcur = __shfl(gv, 0, 64);
    float sum = 0.0f, mx = 0.0f;
    int cnt = 0;
    for (int i = 0; i < nmax; ++i) {
        int g = __shfl(gv, i, 64);
        if (g != gcur) {
            atomicAdd(&gsum[(size_t)gcur * HID + lane], sum);
            atomicMax(&gmax[(size_t)gcur * HID + lane], __float_as_int(mx));
            if (lane == 0) atomicAdd(&gcnt[gcur], (float)cnt);
            sum = 0.0f; mx = 0.0f; cnt = 0; gcur = g;
        }
        float v = h1[((size_t)base + i) * HID + lane];
        sum += v;
        mx = fmaxf(mx, v);
        cnt++;
    }
    atomicAdd(&gsum[(size_t)gcur * HID + lane], sum);
    atomicMax(&gmax[(size_t)gcur * HID + lane], __float_as_int(mx));
    if (lane == 0) atomicAdd(&gcnt[gcur], (float)cnt);
}

// ---------------- head MLP: one wave per graph ----------------
__global__ __launch_bounds__(64) void head_kernel(const float* __restrict__ gsum,
                                                  const int* __restrict__ gmax,
                                                  const float* __restrict__ gcnt,
                                                  const float* __restrict__ Wc1,
                                                  const float* __restrict__ bc1,
                                                  const float* __restrict__ g3,
                                                  const float* __restrict__ be3,
                                                  const float* __restrict__ Wc2,
                                                  const float* __restrict__ bc2,
                                                  const float* __restrict__ g4,
                                                  const float* __restrict__ be4,
                                                  const float* __restrict__ Wc3,
                                                  const float* __restrict__ bc3,
                                                  float* __restrict__ out) {
    __shared__ float hg[2 * HID];
    __shared__ float t1[HID];
    int g = blockIdx.x;
    int lane = threadIdx.x;

    float cnt = fmaxf(gcnt[g], 1.0f);
    float mean = gsum[(size_t)g * HID + lane] / cnt;
    float mx = __int_as_float(gmax[(size_t)g * HID + lane]);

    float s1 = sqrtf(wave_sum64(mean * mean));
    float a = mean / fmaxf(s1, NORM_EPS);
    float s2 = sqrtf(wave_sum64(mx * mx));
    float bmx = mx / fmaxf(s2, NORM_EPS);

    hg[lane] = a;
    hg[HID + lane] = bmx;
    __syncthreads();

    float y = bc1[lane];
#pragma unroll 8
    for (int k = 0; k < 2 * HID; ++k) {
        y = fmaf(hg[k], Wc1[k * HID + lane], y);
    }
    float mu = wave_sum64(y) * (1.0f / HID);
    float d = y - mu;
    float var = wave_sum64(d * d) * (1.0f / HID);
    float o = d * rsqrtf(var + LN_EPS) * g3[lane] + be3[lane];
    o = fmaxf(o, 0.0f);
    t1[lane] = o;
    __syncthreads();

    float y2 = bc2[lane];
#pragma unroll 8
    for (int k = 0; k < HID; ++k) {
        y2 = fmaf(t1[k], Wc2[k * HID + lane], y2);
    }
    mu = wave_sum64(y2) * (1.0f / HID);
    d = y2 - mu;
    var = wave_sum64(d * d) * (1.0f / HID);
    o = d * rsqrtf(var + LN_EPS) * g4[lane] + be4[lane];
    o = fmaxf(o, 0.0f);

    float v = o * Wc3[lane];
    v = wave_sum64(v);
    if (lane == 0) out[g] = v + bc3[0];
}

extern "C" void kernel_launch(void* const* d_in, const int* in_sizes, int n_in,
                              void* d_out, int out_size, void* d_ws, size_t ws_size,
                              hipStream_t stream) {
    const float* h   = (const float*)d_in[0];
    const int*   src = (const int*)d_in[1];
    const int*   dst = (const int*)d_in[2];
    const int*   gid = (const int*)d_in[3];
    const float* W1  = (const float*)d_in[4];
    const float* b1  = (const float*)d_in[5];
    const float* W2  = (const float*)d_in[6];
    const float* b2  = (const float*)d_in[7];
    const float* g1  = (const float*)d_in[8];
    const float* be1 = (const float*)d_in[9];
    const float* g2  = (const float*)d_in[10];
    const float* be2 = (const float*)d_in[11];
    const float* g3  = (const float*)d_in[12];
    const float* be3 = (const float*)d_in[13];
    const float* g4  = (const float*)d_in[14];
    const float* be4 = (const float*)d_in[15];
    const float* Wc1 = (const float*)d_in[16];
    const float* bc1 = (const float*)d_in[17];
    const float* Wc2 = (const float*)d_in[18];
    const float* bc2 = (const float*)d_in[19];
    const float* Wc3 = (const float*)d_in[20];
    const float* bc3 = (const float*)d_in[21];
    float* out = (float*)d_out;

    const int N = in_sizes[0] / HID;   // 100000
    const int E = in_sizes[1];         // 1200000
    const int G = out_size;            // 512

    // workspace layout (8B-aligned large arrays first)
    char* ws = (char*)d_ws;
    float* h1     = (float*)ws;                                  // N*64 f
    float* h2     = h1 + (size_t)N * HID;                        // N*64 f
    int2*  epack  = (int2*)(h2 + (size_t)N * HID);               // E int2
    float* ns     = (float*)(epack + E);                         // N f
    float* nd     = ns + N;                                      // N f
    int*   cnt_out= (int*)(nd + N);                              // N i (reused as cursor)
    int*   cnt_in = cnt_out + N;                                 // N i
    int*   cs     = cnt_in + N;                                  // N+1 i
    int*   partials = cs + N + 4;                                // 1024 i
    float* gsum   = (float*)(partials + 1024);                   // G*64 f
    int*   gmax   = (int*)(gsum + (size_t)G * HID);              // G*64 i
    float* gcnt   = (float*)(gmax + (size_t)G * HID);            // G f

    const int nch = (N + CHUNK - 1) / CHUNK;

    // zero: histograms (contiguous 2N ints) + pooling buffers (contiguous G*129)
    hipMemsetAsync(cnt_out, 0, sizeof(int) * (size_t)2 * N, stream);
    hipMemsetAsync(gsum, 0, sizeof(float) * (size_t)G * (2 * HID + 1), stream);

    // CSR build
    count_kernel<<<(E + 255) / 256, 256, 0, stream>>>(src, dst, cnt_out, cnt_in, E);
    norm_kernel<<<(N + 255) / 256, 256, 0, stream>>>(cnt_out, cnt_in, ns, nd, N);
    scan1_kernel<<<nch, 256, 0, stream>>>(cnt_in, cs, partials, N);
    scan2_kernel<<<1, 256, 0, stream>>>(partials, nch);
    scan3_kernel<<<(N + 255) / 256, 256, 0, stream>>>(cs, partials, N, E);
    fill_kernel<<<(E + 255) / 256, 256, 0, stream>>>(src, dst, ns, cs, cnt_out, epack, E);

    // conv1: h -> h1
    conv_kernel<<<(N + 3) / 4, 256, 0, stream>>>(h, epack, cs, nd, W1, b1, g1, be1, h1, N);
    // conv2: h1 -> h2
    conv_kernel<<<(N + 3) / 4, 256, 0, stream>>>(h1, epack, cs, nd, W2, b2, g2, be2, h2, N);

    // pooling (sorted gids -> segmented)
    int nstrips = (N + 63) / 64;
    pool_kernel<<<(nstrips + 3) / 4, 256, 0, stream>>>(h2, gid, gsum, gmax, gcnt, N);

    // head
    head_kernel<<<G, 64, 0, stream>>>(gsum, gmax, gcnt, Wc1, bc1, g3, be3,
                                      Wc2, bc2, g4, be4, Wc3, bc3, out);
}

// Round 4
// 539.448 us; speedup vs baseline: 4.8128x; 1.1557x over previous
//
#include <hip/hip_runtime.h>
#include <math.h>

#define HID 64
#define LN_EPS 1e-5f
#define NORM_EPS 1e-12f
#define CHUNK 1024
#define CONV_BLOCKS 2048

__device__ __forceinline__ float wave_sum64(float v) {
#pragma unroll
    for (int o = 32; o > 0; o >>= 1) v += __shfl_xor(v, o, 64);
    return v;
}

// ---------------- edge count (int histograms) ----------------
__global__ __launch_bounds__(256) void count_kernel(const int* __restrict__ src,
                                                    const int* __restrict__ dst,
                                                    int* __restrict__ cnt_out,
                                                    int* __restrict__ cnt_in,
                                                    int E) {
    int e = blockIdx.x * 256 + threadIdx.x;
    if (e >= E) return;
    atomicAdd(&cnt_out[src[e]], 1);
    atomicAdd(&cnt_in[dst[e]], 1);
}

// counts -> deg^-0.5 (clamp 1); also zero cnt_out for reuse as fill cursor
__global__ __launch_bounds__(256) void norm_kernel(int* __restrict__ cnt_out,
                                                   const int* __restrict__ cnt_in,
                                                   float* __restrict__ ns,
                                                   float* __restrict__ nd,
                                                   int N) {
    int n = blockIdx.x * 256 + threadIdx.x;
    if (n >= N) return;
    ns[n] = rsqrtf((float)max(cnt_out[n], 1));
    nd[n] = rsqrtf((float)max(cnt_in[n], 1));
    cnt_out[n] = 0;  // reuse as cursor in fill_kernel
}

// ---------------- 2-level exclusive scan of cnt_in -> cs ----------------
__global__ __launch_bounds__(256) void scan1_kernel(const int* __restrict__ cnt,
                                                    int* __restrict__ cs,
                                                    int* __restrict__ partials,
                                                    int N) {
    __shared__ int wsum[4];
    int t = threadIdx.x;
    int lane = t & 63, wave = t >> 6;
    int base = blockIdx.x * CHUNK + t * 4;
    int v0 = (base + 0 < N) ? cnt[base + 0] : 0;
    int v1 = (base + 1 < N) ? cnt[base + 1] : 0;
    int v2 = (base + 2 < N) ? cnt[base + 2] : 0;
    int v3 = (base + 3 < N) ? cnt[base + 3] : 0;
    int tsum = v0 + v1 + v2 + v3;
    int x = tsum;
#pragma unroll
    for (int off = 1; off < 64; off <<= 1) {
        int y = __shfl_up(x, off, 64);
        if (lane >= off) x += y;
    }
    if (lane == 63) wsum[wave] = x;
    __syncthreads();
    int waveoff = 0;
    for (int w = 0; w < wave; ++w) waveoff += wsum[w];
    int off0 = waveoff + x - tsum;
    if (base + 0 < N) cs[base + 0] = off0;
    if (base + 1 < N) cs[base + 1] = off0 + v0;
    if (base + 2 < N) cs[base + 2] = off0 + v0 + v1;
    if (base + 3 < N) cs[base + 3] = off0 + v0 + v1 + v2;
    if (t == 255) partials[blockIdx.x] = waveoff + x;  // block total
}

__global__ __launch_bounds__(256) void scan2_kernel(int* __restrict__ partials, int nch) {
    __shared__ int wsum[4];
    int t = threadIdx.x;
    int lane = t & 63, wave = t >> 6;
    int base = t * 4;
    int v0 = (base + 0 < nch) ? partials[base + 0] : 0;
    int v1 = (base + 1 < nch) ? partials[base + 1] : 0;
    int v2 = (base + 2 < nch) ? partials[base + 2] : 0;
    int v3 = (base + 3 < nch) ? partials[base + 3] : 0;
    int tsum = v0 + v1 + v2 + v3;
    int x = tsum;
#pragma unroll
    for (int off = 1; off < 64; off <<= 1) {
        int y = __shfl_up(x, off, 64);
        if (lane >= off) x += y;
    }
    if (lane == 63) wsum[wave] = x;
    __syncthreads();
    int waveoff = 0;
    for (int w = 0; w < wave; ++w) waveoff += wsum[w];
    int off0 = waveoff + x - tsum;
    if (base + 0 < nch) partials[base + 0] = off0;
    if (base + 1 < nch) partials[base + 1] = off0 + v0;
    if (base + 2 < nch) partials[base + 2] = off0 + v0 + v1;
    if (base + 3 < nch) partials[base + 3] = off0 + v0 + v1 + v2;
}

__global__ __launch_bounds__(256) void scan3_kernel(int* __restrict__ cs,
                                                    const int* __restrict__ partials,
                                                    int N, int E) {
    int n = blockIdx.x * 256 + threadIdx.x;
    if (n < N) cs[n] += partials[n / CHUNK];
    if (n == 0) cs[N] = E;
}

// ---------------- fill CSR buckets: epack[slot] = (src, ns[src]) ----------------
__global__ __launch_bounds__(256) void fill_kernel(const int* __restrict__ src,
                                                   const int* __restrict__ dst,
                                                   const float* __restrict__ ns,
                                                   const int* __restrict__ cs,
                                                   int* __restrict__ cursor,
                                                   int2* __restrict__ epack,
                                                   int E) {
    int e = blockIdx.x * 256 + threadIdx.x;
    if (e >= E) return;
    int s = src[e];
    int d = dst[e];
    float w = ns[s];
    int p = cs[d] + atomicAdd(&cursor[d], 1);
    epack[p] = make_int2(s, __float_as_int(w));
}

// ---------------- fused conv: gather + (·nd)@W + b -> LN -> relu ----------------
// grid-stride, 4 waves/block, one wave per node; 4x-unrolled gather for MLP.
__global__ __launch_bounds__(256) void conv_kernel(const float* __restrict__ x,
                                                   const int2* __restrict__ epack,
                                                   const int* __restrict__ cs,
                                                   const float* __restrict__ nd,
                                                   const float* __restrict__ W,
                                                   const float* __restrict__ b,
                                                   const float* __restrict__ gam,
                                                   const float* __restrict__ bet,
                                                   float* __restrict__ out,
                                                   int N) {
    __shared__ float Ws[HID * HID];
    int tid = threadIdx.x;
    for (int i = tid; i < HID * HID / 4; i += 256) {
        reinterpret_cast<float4*>(Ws)[i] = reinterpret_cast<const float4*>(W)[i];
    }
    __syncthreads();
    int wave = tid >> 6;
    int lane = tid & 63;
    float bl = b[lane], gl = gam[lane], bel = bet[lane];

    for (int n = blockIdx.x * 4 + wave; n < N; n += CONV_BLOCKS * 4) {
        int beg = cs[n], end = cs[n + 1];
        float acc = 0.0f;
        int e = beg;
        // 4-way unrolled gather: 4 independent epack + 4 independent row loads in flight
        for (; e + 4 <= end; e += 4) {
            int2 p0 = epack[e + 0];
            int2 p1 = epack[e + 1];
            int2 p2 = epack[e + 2];
            int2 p3 = epack[e + 3];
            float v0 = x[(size_t)p0.x * HID + lane];
            float v1 = x[(size_t)p1.x * HID + lane];
            float v2 = x[(size_t)p2.x * HID + lane];
            float v3 = x[(size_t)p3.x * HID + lane];
            acc = fmaf(v0, __int_as_float(p0.y), acc);
            acc = fmaf(v1, __int_as_float(p1.y), acc);
            acc = fmaf(v2, __int_as_float(p2.y), acc);
            acc = fmaf(v3, __int_as_float(p3.y), acc);
        }
        for (; e < end; ++e) {
            int2 p = epack[e];
            acc = fmaf(x[(size_t)p.x * HID + lane], __int_as_float(p.y), acc);
        }
        float t = acc * nd[n];

        // y[lane] = sum_k t_k * Ws[k][lane] + b ; broadcast t_k via shfl
        float y = bl;
#pragma unroll
        for (int k = 0; k < HID; ++k) {
            y = fmaf(__shfl(t, k, 64), Ws[k * HID + lane], y);
        }
        float mu = wave_sum64(y) * (1.0f / HID);
        float d = y - mu;
        float var = wave_sum64(d * d) * (1.0f / HID);
        float o = d * rsqrtf(var + LN_EPS) * gl + bel;
        o = fmaxf(o, 0.0f);
        out[(size_t)n * HID + lane] = o;
    }
}

// ---------------- segmented pooling over sorted graph_ids ----------------
__global__ __launch_bounds__(256) void pool_kernel(const float* __restrict__ h1,
                                                   const int* __restrict__ gid,
                                                   float* __restrict__ gsum,
                                                   int* __restrict__ gmax,   // float bits, vals >= 0
                                                   float* __restrict__ gcnt,
                                                   int N) {
    int wave = threadIdx.x >> 6;
    int lane = threadIdx.x & 63;
    int strip = blockIdx.x * 4 + wave;
    int base = strip * 64;
    if (base >= N) return;
    int nmax = min(64, N - base);
    int gv = (base + lane < N) ? gid[base + lane] : -1;
    int gcur = __shfl(gv, 0, 64);
    float sum = 0.0f, mx = 0.0f;
    int cnt = 0;
    for (int i = 0; i < nmax; ++i) {
        int g = __shfl(gv, i, 64);
        if (g != gcur) {
            atomicAdd(&gsum[(size_t)gcur * HID + lane], sum);
            atomicMax(&gmax[(size_t)gcur * HID + lane], __float_as_int(mx));
            if (lane == 0) atomicAdd(&gcnt[gcur], (float)cnt);
            sum = 0.0f; mx = 0.0f; cnt = 0; gcur = g;
        }
        float v = h1[((size_t)base + i) * HID + lane];
        sum += v;
        mx = fmaxf(mx, v);
        cnt++;
    }
    atomicAdd(&gsum[(size_t)gcur * HID + lane], sum);
    atomicMax(&gmax[(size_t)gcur * HID + lane], __float_as_int(mx));
    if (lane == 0) atomicAdd(&gcnt[gcur], (float)cnt);
}

// ---------------- head MLP: one wave per graph ----------------
__global__ __launch_bounds__(64) void head_kernel(const float* __restrict__ gsum,
                                                  const int* __restrict__ gmax,
                                                  const float* __restrict__ gcnt,
                                                  const float* __restrict__ Wc1,
                                                  const float* __restrict__ bc1,
                                                  const float* __restrict__ g3,
                                                  const float* __restrict__ be3,
                                                  const float* __restrict__ Wc2,
                                                  const float* __restrict__ bc2,
                                                  const float* __restrict__ g4,
                                                  const float* __restrict__ be4,
                                                  const float* __restrict__ Wc3,
                                                  const float* __restrict__ bc3,
                                                  float* __restrict__ out) {
    __shared__ float hg[2 * HID];
    __shared__ float t1[HID];
    int g = blockIdx.x;
    int lane = threadIdx.x;

    float cnt = fmaxf(gcnt[g], 1.0f);
    float mean = gsum[(size_t)g * HID + lane] / cnt;
    float mx = __int_as_float(gmax[(size_t)g * HID + lane]);

    float s1 = sqrtf(wave_sum64(mean * mean));
    float a = mean / fmaxf(s1, NORM_EPS);
    float s2 = sqrtf(wave_sum64(mx * mx));
    float bmx = mx / fmaxf(s2, NORM_EPS);

    hg[lane] = a;
    hg[HID + lane] = bmx;
    __syncthreads();

    float y = bc1[lane];
#pragma unroll 8
    for (int k = 0; k < 2 * HID; ++k) {
        y = fmaf(hg[k], Wc1[k * HID + lane], y);
    }
    float mu = wave_sum64(y) * (1.0f / HID);
    float d = y - mu;
    float var = wave_sum64(d * d) * (1.0f / HID);
    float o = d * rsqrtf(var + LN_EPS) * g3[lane] + be3[lane];
    o = fmaxf(o, 0.0f);
    t1[lane] = o;
    __syncthreads();

    float y2 = bc2[lane];
#pragma unroll 8
    for (int k = 0; k < HID; ++k) {
        y2 = fmaf(t1[k], Wc2[k * HID + lane], y2);
    }
    mu = wave_sum64(y2) * (1.0f / HID);
    d = y2 - mu;
    var = wave_sum64(d * d) * (1.0f / HID);
    o = d * rsqrtf(var + LN_EPS) * g4[lane] + be4[lane];
    o = fmaxf(o, 0.0f);

    float v = o * Wc3[lane];
    v = wave_sum64(v);
    if (lane == 0) out[g] = v + bc3[0];
}

extern "C" void kernel_launch(void* const* d_in, const int* in_sizes, int n_in,
                              void* d_out, int out_size, void* d_ws, size_t ws_size,
                              hipStream_t stream) {
    const float* h   = (const float*)d_in[0];
    const int*   src = (const int*)d_in[1];
    const int*   dst = (const int*)d_in[2];
    const int*   gid = (const int*)d_in[3];
    const float* W1  = (const float*)d_in[4];
    const float* b1  = (const float*)d_in[5];
    const float* W2  = (const float*)d_in[6];
    const float* b2  = (const float*)d_in[7];
    const float* g1  = (const float*)d_in[8];
    const float* be1 = (const float*)d_in[9];
    const float* g2  = (const float*)d_in[10];
    const float* be2 = (const float*)d_in[11];
    const float* g3  = (const float*)d_in[12];
    const float* be3 = (const float*)d_in[13];
    const float* g4  = (const float*)d_in[14];
    const float* be4 = (const float*)d_in[15];
    const float* Wc1 = (const float*)d_in[16];
    const float* bc1 = (const float*)d_in[17];
    const float* Wc2 = (const float*)d_in[18];
    const float* bc2 = (const float*)d_in[19];
    const float* Wc3 = (const float*)d_in[20];
    const float* bc3 = (const float*)d_in[21];
    float* out = (float*)d_out;

    const int N = in_sizes[0] / HID;   // 100000
    const int E = in_sizes[1];         // 1200000
    const int G = out_size;            // 512

    // workspace layout (8B-aligned large arrays first)
    char* ws = (char*)d_ws;
    float* h1     = (float*)ws;                                  // N*64 f
    float* h2     = h1 + (size_t)N * HID;                        // N*64 f
    int2*  epack  = (int2*)(h2 + (size_t)N * HID);               // E int2
    float* ns     = (float*)(epack + E);                         // N f
    float* nd     = ns + N;                                      // N f
    int*   cnt_out= (int*)(nd + N);                              // N i (reused as cursor)
    int*   cnt_in = cnt_out + N;                                 // N i
    int*   cs     = cnt_in + N;                                  // N+1 i
    int*   partials = cs + N + 4;                                // 1024 i
    float* gsum   = (float*)(partials + 1024);                   // G*64 f
    int*   gmax   = (int*)(gsum + (size_t)G * HID);              // G*64 i
    float* gcnt   = (float*)(gmax + (size_t)G * HID);            // G f

    const int nch = (N + CHUNK - 1) / CHUNK;

    hipMemsetAsync(cnt_out, 0, sizeof(int) * (size_t)2 * N, stream);
    hipMemsetAsync(gsum, 0, sizeof(float) * (size_t)G * (2 * HID + 1), stream);

    // CSR build
    count_kernel<<<(E + 255) / 256, 256, 0, stream>>>(src, dst, cnt_out, cnt_in, E);
    norm_kernel<<<(N + 255) / 256, 256, 0, stream>>>(cnt_out, cnt_in, ns, nd, N);
    scan1_kernel<<<nch, 256, 0, stream>>>(cnt_in, cs, partials, N);
    scan2_kernel<<<1, 256, 0, stream>>>(partials, nch);
    scan3_kernel<<<(N + 255) / 256, 256, 0, stream>>>(cs, partials, N, E);
    fill_kernel<<<(E + 255) / 256, 256, 0, stream>>>(src, dst, ns, cs, cnt_out, epack, E);

    // conv1: h -> h1
    conv_kernel<<<CONV_BLOCKS, 256, 0, stream>>>(h, epack, cs, nd, W1, b1, g1, be1, h1, N);
    // conv2: h1 -> h2
    conv_kernel<<<CONV_BLOCKS, 256, 0, stream>>>(h1, epack, cs, nd, W2, b2, g2, be2, h2, N);

    // pooling (sorted gids -> segmented)
    int nstrips = (N + 63) / 64;
    pool_kernel<<<(nstrips + 3) / 4, 256, 0, stream>>>(h2, gid, gsum, gmax, gcnt, N);

    // head
    head_kernel<<<G, 64, 0, stream>>>(gsum, gmax, gcnt, Wc1, bc1, g3, be3,
                                      Wc2, bc2, g4, be4, Wc3, bc3, out);
}